// Round 11
// baseline (1416.376 us; speedup 1.0000x reference)
//
#include <hip/hip_runtime.h>
#include <stdint.h>
#include <math.h>

#define N_ROWS 2048
#define M_CAND 131072
#define DIMK 128
#define DOUT 10
#define COLS_PER_BLOCK 1024       // one chunk per block (class-uniform, padded)
#define SUB_ITERS 16              // fixed trip count (R8 dynamic bound regressed 13%)
#define CHUNKS_MAX 138            // ceil(M/1024) + DOUT (class-padding worst case)
#define M_PAD_MAX (CHUNKS_MAX * COLS_PER_BLOCK)   // 141312
#define NBLK_X (N_ROWS / 64)      // 32 encoder blocks for x
#define LOG2E 1.4426950408889634f
#define L2E2 (LOG2E * LOG2E)      // norms pre-scaled: exp2(-sqrt(sq')) == exp(-sqrt(sq))

typedef __attribute__((ext_vector_type(8))) __bf16 bf16x8;   // MFMA A/B frag (4 VGPRs)
typedef __attribute__((ext_vector_type(8))) short s16x8;     // raw bf16 storage vec
typedef __attribute__((ext_vector_type(4))) float f32x4;     // MFMA C/D frag
typedef __attribute__((ext_vector_type(2))) float f32x2;     // v_pk_* pair
typedef __attribute__((address_space(3))) void lds_void;
typedef const __attribute__((address_space(1))) void gbl_void;

union frag_cast { s16x8 s; bf16x8 b; };

__device__ __forceinline__ short f2bf(float f) {   // RNE fp32->bf16
  union { float f; unsigned u; } v; v.f = f;
  return (short)((v.u + 0x7fffu + ((v.u >> 16) & 1u)) >> 16);
}
__device__ __forceinline__ float bf2f(short h) {
  union { unsigned u; float f; } v;
  v.u = ((unsigned)(unsigned short)h) << 16; return v.f;
}
__device__ __forceinline__ float fast_sqrtf(float x) {
#if __has_builtin(__builtin_amdgcn_sqrtf)
  return __builtin_amdgcn_sqrtf(x);
#else
  return sqrtf(x);
#endif
}
__device__ __forceinline__ float fast_exp2f(float x) {
#if __has_builtin(__builtin_amdgcn_exp2f)
  return __builtin_amdgcn_exp2f(x);
#else
  return exp2f(x);
#endif
}

// Swizzled 64x128 bf16 tile: LDS slot (r,s) [16B granules] holds global granule g = s^(r&15).
__device__ __forceinline__ void stage64(const short* gbase, short* lds, int t) {
  int w = t >> 6;
#pragma unroll
  for (int i = 0; i < 4; ++i) {
    int flat = i * 256 + t;
    int r = flat >> 4, s = flat & 15;
    int g = s ^ (r & 15);
    const short* src = gbase + r * DIMK + g * 8;
    short* dst = lds + (i * 256 + w * 64) * 8;   // wave-uniform base; HW adds lane*16B
    __builtin_amdgcn_global_load_lds((gbl_void*)src, (lds_void*)dst, 16, 0, 0);
  }
}

// Swizzled 128x128 bf16 tile stage (encoder: W)
__device__ __forceinline__ void stage128(const short* gbase, short* lds, int t) {
  int w = t >> 6;
#pragma unroll
  for (int i = 0; i < 8; ++i) {
    int flat = i * 256 + t;
    int r = flat >> 4, s = flat & 15;
    int g = s ^ (r & 15);
    const short* src = gbase + r * DIMK + g * 8;
    short* dst = lds + (i * 256 + w * 64) * 8;
    __builtin_amdgcn_global_load_lds((gbl_void*)src, (lds_void*)dst, 16, 0, 0);
  }
}

// 32-row x 64-col wave tile MFMA block (K=128) from a swizzled 64x128 LDS tile
__device__ __forceinline__ void mfma_block(const short* B, const bf16x8 afrag[4][2],
                                           f32x4 acc[2][4], int quad, int l15) {
  f32x4 z4 = {0.f, 0.f, 0.f, 0.f};
#pragma unroll
  for (int ti = 0; ti < 2; ++ti)
#pragma unroll
    for (int j = 0; j < 4; ++j) acc[ti][j] = z4;
#pragma unroll
  for (int ks = 0; ks < 4; ++ks) {
    int slot = (ks * 4 + quad) ^ l15;
    const short* p = B + l15 * DIMK + slot * 8;   // imm offsets encode j*16 rows
    bf16x8 b0 = *(const bf16x8*)(p);
    bf16x8 b1 = *(const bf16x8*)(p + 16 * DIMK);
    bf16x8 b2 = *(const bf16x8*)(p + 32 * DIMK);
    bf16x8 b3 = *(const bf16x8*)(p + 48 * DIMK);
#pragma unroll
    for (int ti = 0; ti < 2; ++ti) {
      acc[ti][0] = __builtin_amdgcn_mfma_f32_16x16x32_bf16(afrag[ks][ti], b0, acc[ti][0], 0, 0, 0);
      acc[ti][1] = __builtin_amdgcn_mfma_f32_16x16x32_bf16(afrag[ks][ti], b1, acc[ti][1], 0, 0, 0);
      acc[ti][2] = __builtin_amdgcn_mfma_f32_16x16x32_bf16(afrag[ks][ti], b2, acc[ti][2], 0, 0, 0);
      acc[ti][3] = __builtin_amdgcn_mfma_f32_16x16x32_bf16(afrag[ks][ti], b3, acc[ti][3], 0, 0, 0);
    }
  }
}

// dist+exp epilogue on a finished accumulator (independent of current MFMAs)
__device__ __forceinline__ void epilogue(const f32x4 acc[2][4], const float sqcv[4],
                                         const f32x2 szv2[2][2], f32x2 sum2[4]) {
  const f32x2 m2 = {-2.0f * L2E2, -2.0f * L2E2};
#pragma unroll
  for (int ti = 0; ti < 2; ++ti)
#pragma unroll
    for (int j = 0; j < 4; ++j) {
      f32x2 q = {sqcv[j], sqcv[j]};
      f32x2 s01 = szv2[ti][0] + q;            // v_pk_add_f32
      f32x2 s23 = szv2[ti][1] + q;
      f32x4 a = acc[ti][j];
      f32x2 a01 = {a[0], a[1]}, a23 = {a[2], a[3]};
      s01 = a01 * m2 + s01;                   // v_pk_fma_f32
      s23 = a23 * m2 + s23;
      float e0 = fast_exp2f(-fast_sqrtf(__builtin_fabsf(s01[0])));
      float e1 = fast_exp2f(-fast_sqrtf(__builtin_fabsf(s01[1])));
      float e2 = fast_exp2f(-fast_sqrtf(__builtin_fabsf(s23[0])));
      float e3 = fast_exp2f(-fast_sqrtf(__builtin_fabsf(s23[1])));
      sum2[ti * 2 + 0] += (f32x2){e0, e1};
      sum2[ti * 2 + 1] += (f32x2){e2, e3};
    }
}

// ---------------- hist (+ W conversion + accum zeroing folded in) ----------------
__global__ __launch_bounds__(256) void hist_kernel(const int* __restrict__ y,
                                                   int* __restrict__ cnt,
                                                   const float* __restrict__ W,
                                                   short* __restrict__ Wb,
                                                   float* __restrict__ accum) {
  __shared__ int h[DOUT];
  int t = threadIdx.x;
  int gi = blockIdx.x * 256 + t;
  if (gi < DIMK * DIMK) Wb[gi] = f2bf(W[gi]);
  if (blockIdx.x < 128) accum[blockIdx.x * 256 + t] = 0.f;   // 2048*16 floats
  if (t < DOUT) h[t] = 0;
  __syncthreads();
  atomicAdd(&h[y[gi]], 1);
  __syncthreads();
  if (t < DOUT) cnt[blockIdx.x * DOUT + t] = h[t];
}

// scan: per-block exclusive offsets into padded class layout + chunk classes + Sqc pads
__global__ __launch_bounds__(512) void scan_kernel(const int* __restrict__ cnt,
                                                   int* __restrict__ blockoff,
                                                   int* __restrict__ chunk_class,
                                                   float* __restrict__ Sqc) {
  __shared__ int buf[2][512 * DOUT];
  __shared__ int pbnd[DOUT + 1];
  __shared__ int ccnt[DOUT];
  int t = threadIdx.x;
  int v[DOUT];
#pragma unroll
  for (int c = 0; c < DOUT; ++c) { v[c] = cnt[t * DOUT + c]; buf[0][t * DOUT + c] = v[c]; }
  __syncthreads();
  int src = 0;
  for (int off = 1; off < 512; off <<= 1) {
    int x[DOUT];
#pragma unroll
    for (int c = 0; c < DOUT; ++c) {
      x[c] = buf[src][t * DOUT + c];
      if (t >= off) x[c] += buf[src][(t - off) * DOUT + c];
    }
#pragma unroll
    for (int c = 0; c < DOUT; ++c) buf[1 - src][t * DOUT + c] = x[c];
    src ^= 1;
    __syncthreads();
  }
  if (t == 0) {
    int pb = 0;
    pbnd[0] = 0;
    for (int c = 0; c < DOUT; ++c) {
      int tot = buf[src][511 * DOUT + c];
      ccnt[c] = tot;
      pb += (tot + COLS_PER_BLOCK - 1) & ~(COLS_PER_BLOCK - 1);  // pad class to 1024
      pbnd[c + 1] = pb;
    }
  }
  __syncthreads();
  if (t < CHUNKS_MAX) {
    int col = t * COLS_PER_BLOCK, c = 0;
#pragma unroll
    for (int k = 1; k < DOUT; ++k) c += (col >= pbnd[k]) ? 1 : 0;
    chunk_class[t] = c;             // dead chunks -> class 9; they contribute exactly 0
  }
  // Sqc pad slots -> 1e30 (exp flushes to 0; Cb garbage there is harmless)
  for (int c = 0; c < DOUT; ++c) {
    int b = pbnd[c] + ccnt[c], e = pbnd[c + 1];
    for (int i = b + t; i < e; i += 512) Sqc[i] = 1e30f;
  }
  for (int i = pbnd[DOUT] + t; i < M_PAD_MAX; i += 512) Sqc[i] = 1e30f;
#pragma unroll
  for (int c = 0; c < DOUT; ++c)
    blockoff[t * DOUT + c] = pbnd[c] + buf[src][t * DOUT + c] - v[c];  // padded exclusive
}

// scatter: forward perm via block-local LDS cursors (R9 lesson: global atomics
// with used return values serialize — 443 us)
__global__ __launch_bounds__(256) void scatter_kernel(const int* __restrict__ y,
                                                      const int* __restrict__ blockoff,
                                                      int* __restrict__ perm) {
  __shared__ int cur[DOUT];
  int t = threadIdx.x;
  if (t < DOUT) cur[t] = blockoff[blockIdx.x * DOUT + t];
  __syncthreads();
  int e = blockIdx.x * 256 + t;
  perm[e] = atomicAdd(&cur[y[e]], 1);
}

// ---------------- fused encoder: blocks 0..31 -> x/Zb, 32.. -> cx/Cb ----------
__global__ __launch_bounds__(256, 4) void encoder_kernel(
    const float* __restrict__ X, const float* __restrict__ CX,
    const short* __restrict__ Wb, const float* __restrict__ bias,
    const int* __restrict__ perm,
    short* __restrict__ Zb, short* __restrict__ Cb,
    float* __restrict__ Sqz, float* __restrict__ Sqc) {
  __shared__ __align__(16) short Ws[DIMK * DIMK];   // 32 KB swizzled W tile
  int t = threadIdx.x;
  int lane = t & 63, wid = t >> 6;
  int quad = lane >> 4, l15 = lane & 15;
  bool is_x = blockIdx.x < NBLK_X;
  int rowbase = (is_x ? blockIdx.x : blockIdx.x - NBLK_X) * 64 + wid * 16;
  const float* src = is_x ? X : CX;
  short* outZ = is_x ? Zb : Cb;
  float* outS = is_x ? Sqz : Sqc;

  stage128(Wb, Ws, t);

  bf16x8 afrag[4];
#pragma unroll
  for (int ks = 0; ks < 4; ++ks) {
    frag_cast fc;
    const float* p = src + (size_t)(rowbase + l15) * DIMK + ks * 32 + quad * 8;
    float4 x0 = *(const float4*)p;
    float4 x1 = *(const float4*)(p + 4);
    fc.s[0] = f2bf(x0.x); fc.s[1] = f2bf(x0.y); fc.s[2] = f2bf(x0.z); fc.s[3] = f2bf(x0.w);
    fc.s[4] = f2bf(x1.x); fc.s[5] = f2bf(x1.y); fc.s[6] = f2bf(x1.z); fc.s[7] = f2bf(x1.w);
    afrag[ks] = fc.b;
  }

  float bias_v[8];
#pragma unroll
  for (int j = 0; j < 8; ++j) bias_v[j] = bias[j * 16 + l15];

  int orow[4];                              // sorted output rows for this lane's C-rows
#pragma unroll
  for (int r = 0; r < 4; ++r) {
    int rr = rowbase + quad * 4 + r;
    orow[r] = is_x ? rr : perm[rr];
  }

  __syncthreads();                          // W staged (vmcnt drained here)

  f32x4 acc[8];
#pragma unroll
  for (int j = 0; j < 8; ++j) acc[j] = (f32x4){0.f, 0.f, 0.f, 0.f};

#pragma unroll
  for (int ks = 0; ks < 4; ++ks) {
    int slot = (ks * 4 + quad) ^ l15;
    const short* p = Ws + l15 * DIMK + slot * 8;   // imm offsets encode j*16 rows
#pragma unroll
    for (int j = 0; j < 8; ++j) {
      bf16x8 b = *(const bf16x8*)(p + j * 16 * DIMK);
      acc[j] = __builtin_amdgcn_mfma_f32_16x16x32_bf16(afrag[ks], b, acc[j], 0, 0, 0);
    }
  }

  float sqp[4] = {0.f, 0.f, 0.f, 0.f};
#pragma unroll
  for (int j = 0; j < 8; ++j) {
#pragma unroll
    for (int r = 0; r < 4; ++r) {
      float z = acc[j][r] + bias_v[j];
      short hb = f2bf(z);
      float zr = bf2f(hb);                  // sq from rounded value (consistency)
      sqp[r] = fmaf(zr, zr, sqp[r]);
      __builtin_nontemporal_store(hb, &outZ[(size_t)orow[r] * DIMK + j * 16 + l15]);
    }
  }
#pragma unroll
  for (int r = 0; r < 4; ++r) {
    float s = sqp[r];
    s += __shfl_xor(s, 1);
    s += __shfl_xor(s, 2);
    s += __shfl_xor(s, 4);
    s += __shfl_xor(s, 8);
    if (l15 == 0)
      __builtin_nontemporal_store(s * L2E2, &outS[orow[r]]);  // pre-scaled
  }
}

// ---------------- main fused GEMM + dist + exp, software-pipelined ----------
// Pipelined: MFMAs of iter `it` (acc_c) run concurrently with the epilogue of
// iter `it-1` (acc_p) — independent register streams, so the scheduler packs
// epilogue VALU into the MFMA/staging shadow (R10 showed VALU 59us + MFMA 31us
// nearly SERIAL at 110us wall). Full 16-iter unroll -> rotation is renaming.
// (256,3): VGPR cap ~170 for the ~130-reg footprint — no spill (R4 lesson).
// Output: class-binned device atomicAdd into accum[row][16] (R5-proven).
__global__ __launch_bounds__(256, 3) void nca_main(
    const short* __restrict__ Zb, const short* __restrict__ Cb,
    const float* __restrict__ Sqz, const float* __restrict__ Sqc,
    const int* __restrict__ chunk_class, float* __restrict__ accum) {
  __shared__ __align__(16) short Bs[2][64 * DIMK];   // 2 x 16 KB

  int t = threadIdx.x;
  int lane = t & 63, wid = t >> 6;
  int quad = lane >> 4, l15 = lane & 15;
  int wrow = wid * 32;                 // each wave owns a private 32-row strip
  int rowbase = blockIdx.x * 128;
  int colbase0 = blockIdx.y * COLS_PER_BLOCK;
  int cls = chunk_class[blockIdx.y];

  stage64(Cb + (size_t)colbase0 * DIMK, &Bs[0][0], t);

  // A fragments: A[m=l15][k=quad*8+j] per 16-row tile, direct from global.
  bf16x8 afrag[4][2];
#pragma unroll
  for (int ks = 0; ks < 4; ++ks)
#pragma unroll
    for (int ti = 0; ti < 2; ++ti)
      afrag[ks][ti] = *(const bf16x8*)(
          Zb + (size_t)(rowbase + wrow + ti * 16 + l15) * DIMK + ks * 32 + quad * 8);

  f32x2 szv2[2][2];                    // pre-scaled row norms, packed over r-pairs
#pragma unroll
  for (int ti = 0; ti < 2; ++ti) {
    f32x4 s4 = *(const f32x4*)(Sqz + rowbase + wrow + ti * 16 + quad * 4);
    szv2[ti][0] = (f32x2){s4[0], s4[1]};
    szv2[ti][1] = (f32x2){s4[2], s4[3]};
  }

  f32x2 sum2[4];
#pragma unroll
  for (int i = 0; i < 4; ++i) sum2[i] = (f32x2){0.f, 0.f};

  float sqcv_p[4];                     // candidate norms for the in-flight acc
#pragma unroll
  for (int j = 0; j < 4; ++j) sqcv_p[j] = Sqc[colbase0 + j * 16 + l15];

  __syncthreads();                     // stage(0) drained
  stage64(Cb + (size_t)(colbase0 + 64) * DIMK, &Bs[1][0], t);

  f32x4 acc_p[2][4];
  mfma_block(&Bs[0][0], afrag, acc_p, quad, l15);   // iter 0 -> acc_p

#pragma unroll
  for (int it = 1; it < SUB_ITERS; ++it) {
    float sqcv_c[4];
#pragma unroll
    for (int j = 0; j < 4; ++j) sqcv_c[j] = Sqc[colbase0 + it * 64 + j * 16 + l15];
    __syncthreads();                   // stage(it) drained; prev LDS reads retired
    if (it + 1 < SUB_ITERS)
      stage64(Cb + (size_t)(colbase0 + (it + 1) * 64) * DIMK, &Bs[(it + 1) & 1][0], t);

    f32x4 acc_c[2][4];
    mfma_block(&Bs[it & 1][0], afrag, acc_c, quad, l15);   // iter it
    epilogue(acc_p, sqcv_p, szv2, sum2);                   // iter it-1 (independent)

#pragma unroll
    for (int ti = 0; ti < 2; ++ti)
#pragma unroll
      for (int j = 0; j < 4; ++j) acc_p[ti][j] = acc_c[ti][j];   // renamed by unroll
#pragma unroll
    for (int j = 0; j < 4; ++j) sqcv_p[j] = sqcv_c[j];
  }
  epilogue(acc_p, sqcv_p, szv2, sum2);                     // final iter

  // per-row column-sum across the 16 l15 lanes, then class-binned atomic add
#pragma unroll
  for (int si = 0; si < 8; ++si) {
    float s = sum2[si >> 1][si & 1];
    s += __shfl_xor(s, 1);
    s += __shfl_xor(s, 2);
    s += __shfl_xor(s, 4);
    s += __shfl_xor(s, 8);
    if (l15 == 0) {
      int row = rowbase + wrow + (si >> 2) * 16 + quad * 4 + (si & 3);
      atomicAdd(&accum[row * 16 + cls], s);
    }
  }
}

// ---------------- final: normalize + log ----------------
__global__ __launch_bounds__(256) void logits_kernel(const float* __restrict__ accum,
                                                     float* __restrict__ out) {
  int i = blockIdx.x * 256 + threadIdx.x;
  if (i >= N_ROWS) return;
  float v[DOUT], tot = 0.f;
#pragma unroll
  for (int c = 0; c < DOUT; ++c) { v[c] = accum[i * 16 + c]; tot += v[c]; }
  float inv = 1.0f / tot;
#pragma unroll
  for (int c = 0; c < DOUT; ++c)
    out[(size_t)i * DOUT + c] = logf(fmaf(v[c], inv, 1e-7f));
}

extern "C" void kernel_launch(void* const* d_in, const int* in_sizes, int n_in,
                              void* d_out, int out_size, void* d_ws, size_t ws_size,
                              hipStream_t stream) {
  const float* x = (const float*)d_in[0];      // [2048][128]
  const float* cx = (const float*)d_in[1];     // [131072][128]
  const int* cy = (const int*)d_in[2];         // [131072]
  const float* W = (const float*)d_in[3];      // [128][128]
  const float* bias = (const float*)d_in[4];   // [128]
  float* out = (float*)d_out;
  char* ws = (char*)d_ws;

  size_t off = 0;
  auto alloc = [&](size_t bytes) {
    void* p = ws + off;
    off = (off + bytes + 255) & ~(size_t)255;
    return p;
  };
  short* Zb = (short*)alloc((size_t)N_ROWS * DIMK * 2);
  short* Cb = (short*)alloc((size_t)M_PAD_MAX * DIMK * 2);
  short* Wb = (short*)alloc((size_t)DIMK * DIMK * 2);
  float* Sqz = (float*)alloc((size_t)N_ROWS * 4);
  float* Sqc = (float*)alloc((size_t)M_PAD_MAX * 4);
  int* perm = (int*)alloc((size_t)M_CAND * 4);
  int* cnt = (int*)alloc(512 * DOUT * 4);
  int* blockoff = (int*)alloc(512 * DOUT * 4);
  int* chunk_class = (int*)alloc(CHUNKS_MAX * 4);
  float* accum = (float*)alloc((size_t)N_ROWS * 16 * 4);
  if (off > ws_size) return;   // ~38 MB needed

  hist_kernel<<<M_CAND / 256, 256, 0, stream>>>(cy, cnt, W, Wb, accum);
  scan_kernel<<<1, 512, 0, stream>>>(cnt, blockoff, chunk_class, Sqc);
  scatter_kernel<<<M_CAND / 256, 256, 0, stream>>>(cy, blockoff, perm);
  encoder_kernel<<<NBLK_X + M_CAND / 64, 256, 0, stream>>>(
      x, cx, Wb, bias, perm, Zb, Cb, Sqz, Sqc);
  nca_main<<<dim3(N_ROWS / 128, CHUNKS_MAX), 256, 0, stream>>>(
      Zb, Cb, Sqz, Sqc, chunk_class, accum);
  logits_kernel<<<(N_ROWS + 255) / 256, 256, 0, stream>>>(accum, out);
}

// Round 12
// 232.266 us; speedup vs baseline: 6.0981x; 6.0981x over previous
//
#include <hip/hip_runtime.h>
#include <stdint.h>
#include <math.h>

#define N_ROWS 2048
#define M_CAND 131072
#define DIMK 128
#define DOUT 10
#define COLS_PER_BLOCK 1024       // one chunk per block (class-uniform, padded)
#define SUB_ITERS 16              // fixed trip count (R8 dynamic bound regressed 13%)
#define CHUNKS_MAX 138            // ceil(M/1024) + DOUT (class-padding worst case)
#define M_PAD_MAX (CHUNKS_MAX * COLS_PER_BLOCK)   // 141312
#define NBLK_X (N_ROWS / 64)      // 32 encoder blocks for x
#define LOG2E 1.4426950408889634f
#define L2E2 (LOG2E * LOG2E)      // norms pre-scaled: exp2(-sqrt(sq')) == exp(-sqrt(sq))

typedef __attribute__((ext_vector_type(8))) __bf16 bf16x8;   // MFMA A/B frag (4 VGPRs)
typedef __attribute__((ext_vector_type(8))) short s16x8;     // raw bf16 storage vec
typedef __attribute__((ext_vector_type(4))) float f32x4;     // MFMA C/D frag
typedef __attribute__((ext_vector_type(2))) float f32x2;     // v_pk_* pair
typedef __attribute__((address_space(3))) void lds_void;
typedef const __attribute__((address_space(1))) void gbl_void;

union frag_cast { s16x8 s; bf16x8 b; };

__device__ __forceinline__ short f2bf(float f) {   // RNE fp32->bf16
  union { float f; unsigned u; } v; v.f = f;
  return (short)((v.u + 0x7fffu + ((v.u >> 16) & 1u)) >> 16);
}
__device__ __forceinline__ float bf2f(short h) {
  union { unsigned u; float f; } v;
  v.u = ((unsigned)(unsigned short)h) << 16; return v.f;
}
__device__ __forceinline__ float fast_sqrtf(float x) {
#if __has_builtin(__builtin_amdgcn_sqrtf)
  return __builtin_amdgcn_sqrtf(x);
#else
  return sqrtf(x);
#endif
}
__device__ __forceinline__ float fast_exp2f(float x) {
#if __has_builtin(__builtin_amdgcn_exp2f)
  return __builtin_amdgcn_exp2f(x);
#else
  return exp2f(x);
#endif
}

// Swizzled 64x128 bf16 tile: LDS slot (r,s) [16B granules] holds global granule g = s^(r&15).
__device__ __forceinline__ void stage64(const short* gbase, short* lds, int t) {
  int w = t >> 6;
#pragma unroll
  for (int i = 0; i < 4; ++i) {
    int flat = i * 256 + t;
    int r = flat >> 4, s = flat & 15;
    int g = s ^ (r & 15);
    const short* src = gbase + r * DIMK + g * 8;
    short* dst = lds + (i * 256 + w * 64) * 8;   // wave-uniform base; HW adds lane*16B
    __builtin_amdgcn_global_load_lds((gbl_void*)src, (lds_void*)dst, 16, 0, 0);
  }
}

// Swizzled 128x128 bf16 tile stage (encoder: W)
__device__ __forceinline__ void stage128(const short* gbase, short* lds, int t) {
  int w = t >> 6;
#pragma unroll
  for (int i = 0; i < 8; ++i) {
    int flat = i * 256 + t;
    int r = flat >> 4, s = flat & 15;
    int g = s ^ (r & 15);
    const short* src = gbase + r * DIMK + g * 8;
    short* dst = lds + (i * 256 + w * 64) * 8;
    __builtin_amdgcn_global_load_lds((gbl_void*)src, (lds_void*)dst, 16, 0, 0);
  }
}

// ---------------- hist (+ W fp32->bf16 conversion folded in) ----------------
__global__ __launch_bounds__(256) void hist_kernel(const int* __restrict__ y,
                                                   int* __restrict__ cnt,
                                                   const float* __restrict__ W,
                                                   short* __restrict__ Wb) {
  __shared__ int h[DOUT];
  int t = threadIdx.x;
  int gi = blockIdx.x * 256 + t;
  if (gi < DIMK * DIMK) Wb[gi] = f2bf(W[gi]);
  if (t < DOUT) h[t] = 0;
  __syncthreads();
  atomicAdd(&h[y[gi]], 1);
  __syncthreads();
  if (t < DOUT) cnt[blockIdx.x * DOUT + t] = h[t];
}

// scan: per-block exclusive offsets into padded class layout + chunk classes +
// Sqc pads + total padded col count (for dead-chunk early exit).
__global__ __launch_bounds__(512) void scan_kernel(const int* __restrict__ cnt,
                                                   int* __restrict__ blockoff,
                                                   int* __restrict__ chunk_class,
                                                   float* __restrict__ Sqc,
                                                   int* __restrict__ meta) {
  __shared__ int buf[2][512 * DOUT];
  __shared__ int pbnd[DOUT + 1];
  __shared__ int ccnt[DOUT];
  int t = threadIdx.x;
  int v[DOUT];
#pragma unroll
  for (int c = 0; c < DOUT; ++c) { v[c] = cnt[t * DOUT + c]; buf[0][t * DOUT + c] = v[c]; }
  __syncthreads();
  int src = 0;
  for (int off = 1; off < 512; off <<= 1) {
    int x[DOUT];
#pragma unroll
    for (int c = 0; c < DOUT; ++c) {
      x[c] = buf[src][t * DOUT + c];
      if (t >= off) x[c] += buf[src][(t - off) * DOUT + c];
    }
#pragma unroll
    for (int c = 0; c < DOUT; ++c) buf[1 - src][t * DOUT + c] = x[c];
    src ^= 1;
    __syncthreads();
  }
  if (t == 0) {
    int pb = 0;
    pbnd[0] = 0;
    for (int c = 0; c < DOUT; ++c) {
      int tot = buf[src][511 * DOUT + c];
      ccnt[c] = tot;
      pb += (tot + COLS_PER_BLOCK - 1) & ~(COLS_PER_BLOCK - 1);  // pad class to 1024
      pbnd[c + 1] = pb;
    }
    meta[0] = pb;                   // total live (padded) columns
  }
  __syncthreads();
  if (t < CHUNKS_MAX) {
    int col = t * COLS_PER_BLOCK, c = 0;
#pragma unroll
    for (int k = 1; k < DOUT; ++k) c += (col >= pbnd[k]) ? 1 : 0;
    chunk_class[t] = c;             // dead chunks -> class 9; they contribute exactly 0
  }
  // Sqc pad slots -> 1e30 (exp flushes to 0; Cb garbage there is harmless)
  for (int c = 0; c < DOUT; ++c) {
    int b = pbnd[c] + ccnt[c], e = pbnd[c + 1];
    for (int i = b + t; i < e; i += 512) Sqc[i] = 1e30f;
  }
  for (int i = pbnd[DOUT] + t; i < M_PAD_MAX; i += 512) Sqc[i] = 1e30f;
#pragma unroll
  for (int c = 0; c < DOUT; ++c)
    blockoff[t * DOUT + c] = pbnd[c] + buf[src][t * DOUT + c] - v[c];  // padded exclusive
}

// scatter: forward perm via block-local LDS cursors (R9 lesson: global atomics
// with used return values serialize — 443 us)
__global__ __launch_bounds__(256) void scatter_kernel(const int* __restrict__ y,
                                                      const int* __restrict__ blockoff,
                                                      int* __restrict__ perm) {
  __shared__ int cur[DOUT];
  int t = threadIdx.x;
  if (t < DOUT) cur[t] = blockoff[blockIdx.x * DOUT + t];
  __syncthreads();
  int e = blockIdx.x * 256 + t;
  perm[e] = atomicAdd(&cur[y[e]], 1);
}

// ---------------- fused encoder: blocks 0..31 -> x/Zb, 32.. -> cx/Cb ----------
// Only W (bf16, 32 KB) in LDS; A-frags fp32->bf16 in registers from coalesced
// source rows; row-granular scatter-write to sorted slot (no line amplification).
// Cb/Sqc stores nontemporal: keep writebacks out of nca_main's window.
__global__ __launch_bounds__(256, 4) void encoder_kernel(
    const float* __restrict__ X, const float* __restrict__ CX,
    const short* __restrict__ Wb, const float* __restrict__ bias,
    const int* __restrict__ perm,
    short* __restrict__ Zb, short* __restrict__ Cb,
    float* __restrict__ Sqz, float* __restrict__ Sqc) {
  __shared__ __align__(16) short Ws[DIMK * DIMK];   // 32 KB swizzled W tile
  int t = threadIdx.x;
  int lane = t & 63, wid = t >> 6;
  int quad = lane >> 4, l15 = lane & 15;
  bool is_x = blockIdx.x < NBLK_X;
  int rowbase = (is_x ? blockIdx.x : blockIdx.x - NBLK_X) * 64 + wid * 16;
  const float* src = is_x ? X : CX;
  short* outZ = is_x ? Zb : Cb;
  float* outS = is_x ? Sqz : Sqc;

  stage128(Wb, Ws, t);

  bf16x8 afrag[4];
#pragma unroll
  for (int ks = 0; ks < 4; ++ks) {
    frag_cast fc;
    const float* p = src + (size_t)(rowbase + l15) * DIMK + ks * 32 + quad * 8;
    float4 x0 = *(const float4*)p;
    float4 x1 = *(const float4*)(p + 4);
    fc.s[0] = f2bf(x0.x); fc.s[1] = f2bf(x0.y); fc.s[2] = f2bf(x0.z); fc.s[3] = f2bf(x0.w);
    fc.s[4] = f2bf(x1.x); fc.s[5] = f2bf(x1.y); fc.s[6] = f2bf(x1.z); fc.s[7] = f2bf(x1.w);
    afrag[ks] = fc.b;
  }

  float bias_v[8];
#pragma unroll
  for (int j = 0; j < 8; ++j) bias_v[j] = bias[j * 16 + l15];

  int orow[4];                              // sorted output rows for this lane's C-rows
#pragma unroll
  for (int r = 0; r < 4; ++r) {
    int rr = rowbase + quad * 4 + r;
    orow[r] = is_x ? rr : perm[rr];
  }

  __syncthreads();                          // W staged (vmcnt drained here)

  f32x4 acc[8];
#pragma unroll
  for (int j = 0; j < 8; ++j) acc[j] = (f32x4){0.f, 0.f, 0.f, 0.f};

#pragma unroll
  for (int ks = 0; ks < 4; ++ks) {
    int slot = (ks * 4 + quad) ^ l15;
    const short* p = Ws + l15 * DIMK + slot * 8;   // imm offsets encode j*16 rows
#pragma unroll
    for (int j = 0; j < 8; ++j) {
      bf16x8 b = *(const bf16x8*)(p + j * 16 * DIMK);
      acc[j] = __builtin_amdgcn_mfma_f32_16x16x32_bf16(afrag[ks], b, acc[j], 0, 0, 0);
    }
  }

  float sqp[4] = {0.f, 0.f, 0.f, 0.f};
#pragma unroll
  for (int j = 0; j < 8; ++j) {
#pragma unroll
    for (int r = 0; r < 4; ++r) {
      float z = acc[j][r] + bias_v[j];
      short hb = f2bf(z);
      float zr = bf2f(hb);                  // sq from rounded value (consistency)
      sqp[r] = fmaf(zr, zr, sqp[r]);
      __builtin_nontemporal_store(hb, &outZ[(size_t)orow[r] * DIMK + j * 16 + l15]);
    }
  }
#pragma unroll
  for (int r = 0; r < 4; ++r) {
    float s = sqp[r];
    s += __shfl_xor(s, 1);
    s += __shfl_xor(s, 2);
    s += __shfl_xor(s, 4);
    s += __shfl_xor(s, 8);
    if (l15 == 0)
      __builtin_nontemporal_store(s * L2E2, &outS[orow[r]]);  // pre-scaled
  }
}

// ---------------- main fused GEMM + dist + exp + per-block sum ----------
// R10-proven hot loop (R11's acc double-buffer pipelining spilled: 3.6 GB
// scratch traffic, 12x slower — the loop has <~20 VGPRs headroom, period).
// Fixed 16 iters, padded single-class chunks, A-frags register-resident,
// B 64-col sub-tiles double-buffered in exactly 32 KB LDS. Dead padded
// chunks (colbase >= meta[0]) exit early via one wave-uniform compare.
__global__ __launch_bounds__(256, 4) void nca_main(
    const short* __restrict__ Zb, const short* __restrict__ Cb,
    const float* __restrict__ Sqz, const float* __restrict__ Sqc,
    const int* __restrict__ meta, float* __restrict__ partials) {
  __shared__ __align__(16) short Bs[2][64 * DIMK];   // 2 x 16 KB == 32 KB total

  int t = threadIdx.x;
  int rowbase = blockIdx.x * 128;
  int colbase0 = blockIdx.y * COLS_PER_BLOCK;
  if (colbase0 >= meta[0]) {           // dead chunk: zero partials, exit
    if (t < 128) partials[(size_t)blockIdx.y * N_ROWS + rowbase + t] = 0.f;
    return;
  }

  int lane = t & 63, wid = t >> 6;
  int quad = lane >> 4, l15 = lane & 15;
  int wrow = wid * 32;                 // each wave owns a private 32-row strip

  stage64(Cb + (size_t)colbase0 * DIMK, &Bs[0][0], t);

  // A fragments: A[m=l15][k=quad*8+j] per 16-row tile, direct from global.
  bf16x8 afrag[4][2];
#pragma unroll
  for (int ks = 0; ks < 4; ++ks)
#pragma unroll
    for (int ti = 0; ti < 2; ++ti)
      afrag[ks][ti] = *(const bf16x8*)(
          Zb + (size_t)(rowbase + wrow + ti * 16 + l15) * DIMK + ks * 32 + quad * 8);

  f32x2 szv2[2][2];                    // pre-scaled row norms, packed over r-pairs
#pragma unroll
  for (int ti = 0; ti < 2; ++ti) {
    f32x4 s4 = *(const f32x4*)(Sqz + rowbase + wrow + ti * 16 + quad * 4);
    szv2[ti][0] = (f32x2){s4[0], s4[1]};
    szv2[ti][1] = (f32x2){s4[2], s4[3]};
  }

  f32x2 sum2[4];                       // packed accumulators (r-pairs)
#pragma unroll
  for (int i = 0; i < 4; ++i) sum2[i] = (f32x2){0.f, 0.f};

  // norms carry L2E2; cross term must carry the same scale
  const f32x2 m2 = {-2.0f * L2E2, -2.0f * L2E2};

  for (int it = 0; it < SUB_ITERS; ++it) {
    int colb = colbase0 + it * 64;
    __syncthreads();     // drains stage of buf[it&1]; prev-iter reads complete

    // candidate norms straight from global (L2-hot); pads hold 1e30 -> exp == 0
    float sqcv[4];
#pragma unroll
    for (int j = 0; j < 4; ++j) sqcv[j] = Sqc[colb + j * 16 + l15];

    if (it + 1 < SUB_ITERS)
      stage64(Cb + (size_t)(colb + 64) * DIMK, &Bs[(it + 1) & 1][0], t);
    const short* B = &Bs[it & 1][0];

    f32x4 acc[2][4];
    f32x4 z4 = {0.f, 0.f, 0.f, 0.f};
#pragma unroll
    for (int ti = 0; ti < 2; ++ti)
#pragma unroll
      for (int j = 0; j < 4; ++j) acc[ti][j] = z4;

#pragma unroll
    for (int ks = 0; ks < 4; ++ks) {
      int slot = (ks * 4 + quad) ^ l15;
      const short* p = B + l15 * DIMK + slot * 8;   // imm offsets encode j*16 rows
      bf16x8 b0 = *(const bf16x8*)(p);
      bf16x8 b1 = *(const bf16x8*)(p + 16 * DIMK);
      bf16x8 b2 = *(const bf16x8*)(p + 32 * DIMK);
      bf16x8 b3 = *(const bf16x8*)(p + 48 * DIMK);
#pragma unroll
      for (int ti = 0; ti < 2; ++ti) {
        acc[ti][0] = __builtin_amdgcn_mfma_f32_16x16x32_bf16(afrag[ks][ti], b0, acc[ti][0], 0, 0, 0);
        acc[ti][1] = __builtin_amdgcn_mfma_f32_16x16x32_bf16(afrag[ks][ti], b1, acc[ti][1], 0, 0, 0);
        acc[ti][2] = __builtin_amdgcn_mfma_f32_16x16x32_bf16(afrag[ks][ti], b2, acc[ti][2], 0, 0, 0);
        acc[ti][3] = __builtin_amdgcn_mfma_f32_16x16x32_bf16(afrag[ks][ti], b3, acc[ti][3], 0, 0, 0);
      }
    }

#pragma unroll
    for (int ti = 0; ti < 2; ++ti)
#pragma unroll
      for (int j = 0; j < 4; ++j) {
        f32x2 q = {sqcv[j], sqcv[j]};
        f32x2 s01 = szv2[ti][0] + q;            // v_pk_add_f32
        f32x2 s23 = szv2[ti][1] + q;
        f32x4 a = acc[ti][j];
        f32x2 a01 = {a[0], a[1]}, a23 = {a[2], a[3]};
        s01 = a01 * m2 + s01;                   // v_pk_fma_f32
        s23 = a23 * m2 + s23;
        float e0 = fast_exp2f(-fast_sqrtf(__builtin_fabsf(s01[0])));
        float e1 = fast_exp2f(-fast_sqrtf(__builtin_fabsf(s01[1])));
        float e2 = fast_exp2f(-fast_sqrtf(__builtin_fabsf(s23[0])));
        float e3 = fast_exp2f(-fast_sqrtf(__builtin_fabsf(s23[1])));
        sum2[ti * 2 + 0] += (f32x2){e0, e1};    // v_pk_add_f32 accumulate
        sum2[ti * 2 + 1] += (f32x2){e2, e3};
      }
  }

  // per-row column-sum: reduce across the 16 l15 lanes, once per block
#pragma unroll
  for (int si = 0; si < 8; ++si) {
    float s = sum2[si >> 1][si & 1];
    s += __shfl_xor(s, 1);
    s += __shfl_xor(s, 2);
    s += __shfl_xor(s, 4);
    s += __shfl_xor(s, 8);
    if (l15 == 0) {
      int row_l = wrow + (si >> 2) * 16 + quad * 4 + (si & 3);
      partials[(size_t)blockIdx.y * N_ROWS + rowbase + row_l] = s;
    }
  }
}

// ---------------- final reduce over chunks, class binning + log ----------------
__global__ __launch_bounds__(64) void reduce_kernel(const float* __restrict__ partials,
                                                    const int* __restrict__ chunk_class,
                                                    float* __restrict__ out) {
  int row = blockIdx.x, lane = threadIdx.x;
  float s = 0.f;
  for (int ch = 0; ch < CHUNKS_MAX; ++ch) {
    float p = partials[(size_t)ch * N_ROWS + row];
    int c = chunk_class[ch];
    s += (lane == c) ? p : 0.f;
  }
  float tot = s;
  tot += __shfl_xor(tot, 1);
  tot += __shfl_xor(tot, 2);
  tot += __shfl_xor(tot, 4);
  tot += __shfl_xor(tot, 8);
  tot += __shfl_xor(tot, 16);
  tot += __shfl_xor(tot, 32);
  if (lane < DOUT)
    out[(size_t)row * DOUT + lane] = logf(s / tot + 1e-7f);
}

extern "C" void kernel_launch(void* const* d_in, const int* in_sizes, int n_in,
                              void* d_out, int out_size, void* d_ws, size_t ws_size,
                              hipStream_t stream) {
  const float* x = (const float*)d_in[0];      // [2048][128]
  const float* cx = (const float*)d_in[1];     // [131072][128]
  const int* cy = (const int*)d_in[2];         // [131072]
  const float* W = (const float*)d_in[3];      // [128][128]
  const float* bias = (const float*)d_in[4];   // [128]
  float* out = (float*)d_out;
  char* ws = (char*)d_ws;

  size_t off = 0;
  auto alloc = [&](size_t bytes) {
    void* p = ws + off;
    off = (off + bytes + 255) & ~(size_t)255;
    return p;
  };
  short* Zb = (short*)alloc((size_t)N_ROWS * DIMK * 2);
  short* Cb = (short*)alloc((size_t)M_PAD_MAX * DIMK * 2);
  short* Wb = (short*)alloc((size_t)DIMK * DIMK * 2);
  float* Sqz = (float*)alloc((size_t)N_ROWS * 4);
  float* Sqc = (float*)alloc((size_t)M_PAD_MAX * 4);
  int* perm = (int*)alloc((size_t)M_CAND * 4);
  int* cnt = (int*)alloc(512 * DOUT * 4);
  int* blockoff = (int*)alloc(512 * DOUT * 4);
  int* chunk_class = (int*)alloc(CHUNKS_MAX * 4);
  int* meta = (int*)alloc(16 * 4);
  float* partials = (float*)alloc((size_t)CHUNKS_MAX * N_ROWS * 4);
  if (off > ws_size) return;   // ~39 MB needed

  hist_kernel<<<M_CAND / 256, 256, 0, stream>>>(cy, cnt, W, Wb);
  scan_kernel<<<1, 512, 0, stream>>>(cnt, blockoff, chunk_class, Sqc, meta);
  scatter_kernel<<<M_CAND / 256, 256, 0, stream>>>(cy, blockoff, perm);
  encoder_kernel<<<NBLK_X + M_CAND / 64, 256, 0, stream>>>(
      x, cx, Wb, bias, perm, Zb, Cb, Sqz, Sqc);
  nca_main<<<dim3(N_ROWS / 128, CHUNKS_MAX), 256, 0, stream>>>(
      Zb, Cb, Sqz, Sqc, meta, partials);
  reduce_kernel<<<N_ROWS, 64, 0, stream>>>(partials, chunk_class, out);
}